// Round 6
// baseline (433.896 us; speedup 1.0000x reference)
//
#include <hip/hip_runtime.h>
#include <hip/hip_bf16.h>

typedef __hip_bfloat16 bf16;

#define NH   16
#define HD   128
#define SEQ  2048
#define BB   2
#define HID  2048

// ln(10000)/64
#define ROPE_C 0.14391156856f

using frag   = __attribute__((ext_vector_type(8))) short;   // 8 bf16 = 4 VGPRs
using f32x4  = __attribute__((ext_vector_type(4))) float;
using f32x16 = __attribute__((ext_vector_type(16))) float;

// ---------- helpers ----------

// pack 8 fp32 -> 8 bf16 (one 16B LDS write)
__device__ __forceinline__ void cvt8_store(const float4 f0, const float4 f1, bf16* dst) {
    union { frag v; bf16 h[8]; } p;
    p.h[0] = __float2bfloat16(f0.x); p.h[1] = __float2bfloat16(f0.y);
    p.h[2] = __float2bfloat16(f0.z); p.h[3] = __float2bfloat16(f0.w);
    p.h[4] = __float2bfloat16(f1.x); p.h[5] = __float2bfloat16(f1.y);
    p.h[6] = __float2bfloat16(f1.z); p.h[7] = __float2bfloat16(f1.w);
    *reinterpret_cast<frag*>(dst) = p.v;
}

// pack 2 fp32 -> 1 dword of 2 bf16
__device__ __forceinline__ unsigned pk2(float a, float b) {
    union { bf16 h[2]; unsigned u; } p;
    p.h[0] = __float2bfloat16(a);
    p.h[1] = __float2bfloat16(b);
    return p.u;
}

// ---------- fused Q/K/V projection, 8-wave 128x128 tiles (unchanged, passing) ----------
__global__ __launch_bounds__(512) void gemm_qkv(const float* __restrict__ A,
                                                const float* __restrict__ Wq,
                                                const float* __restrict__ Wk,
                                                const float* __restrict__ Wv,
                                                bf16* __restrict__ qout,
                                                float* __restrict__ Ck,
                                                float* __restrict__ Cv,
                                                bf16* __restrict__ kb,
                                                bf16* __restrict__ vt) {
    __shared__ bf16 Asl[4096];   // 128 rows x 32 k (bf16)
    __shared__ bf16 Bsl[4096];
    const int tid  = threadIdx.x;
    const int wave = tid >> 6;
    const int lane = tid & 63;
    const int quad = lane >> 4;
    const int l15  = lane & 15;
    const int row0 = blockIdx.y * 128;
    const int bx   = blockIdx.x;
    const bool isq  = bx < 16;
    const bool is_v = (bx == 17);
    const float* W  = isq ? Wq : (is_v ? Wv : Wk);
    const int col0  = isq ? bx * 128 : 0;

    const int sr = tid >> 2;          // 0..127
    const int sc = (tid & 3) * 8;     // 0,8,16,24

    f32x4 acc[8];
#pragma unroll
    for (int j = 0; j < 8; ++j) acc[j] = (f32x4){0.f,0.f,0.f,0.f};

    for (int k0 = 0; k0 < HID; k0 += 32) {
        __syncthreads();
        {
            const float4* a0 = reinterpret_cast<const float4*>(A + (size_t)(row0 + sr) * HID + k0 + sc);
            const float4* b0 = reinterpret_cast<const float4*>(W + (size_t)(col0 + sr) * HID + k0 + sc);
            cvt8_store(a0[0], a0[1], &Asl[tid * 8]);
            cvt8_store(b0[0], b0[1], &Bsl[tid * 8]);
        }
        __syncthreads();
        frag af, bfr[8];
        af = *reinterpret_cast<const frag*>(&Asl[(((wave*16 + l15)*4) + quad) * 8]);
#pragma unroll
        for (int j = 0; j < 8; ++j)
            bfr[j] = *reinterpret_cast<const frag*>(&Bsl[(((j*16 + l15)*4) + quad) * 8]);
#pragma unroll
        for (int j = 0; j < 8; ++j)
            acc[j] = __builtin_amdgcn_mfma_f32_16x16x32_bf16(af, bfr[j], acc[j], 0, 0, 0);
    }

    if (isq) {
#pragma unroll
        for (int r = 0; r < 4; ++r) {
            const int row = row0 + wave*16 + quad*4 + r;
            const int s = row & (SEQ - 1);
            bf16* crow = qout + (size_t)row * HID + col0;
#pragma unroll
            for (int j = 0; j < 4; ++j) {
                const int d = 16*j + l15;
                const float invf = expf(-(float)d * ROPE_C);
                float sn, cs;
                sincosf((float)s * invf, &sn, &cs);
                const float x1 = acc[j][r], x2 = acc[j+4][r];
                crow[d]      = __float2bfloat16(x1*cs - x2*sn);
                crow[d + 64] = __float2bfloat16(x2*cs + x1*sn);
            }
        }
    } else if (is_v) {
#pragma unroll
        for (int r = 0; r < 4; ++r) {
            const int row = row0 + wave*16 + quad*4 + r;   // b*SEQ + s
            const int s = row & (SEQ - 1);
            const int b = row >> 11;
            float* crow = Cv + (size_t)row * HD;
#pragma unroll
            for (int j = 0; j < 8; ++j) {
                const int d = 16*j + l15;
                const float val = acc[j][r];
                crow[d] = val;
                vt[((size_t)b * HD + d) * SEQ + s] = __float2bfloat16(val);
            }
        }
    } else {
#pragma unroll
        for (int r = 0; r < 4; ++r) {
            const int row = row0 + wave*16 + quad*4 + r;
            const int s = row & (SEQ - 1);
            float* crow = Ck + (size_t)row * HD;
#pragma unroll
            for (int j = 0; j < 4; ++j) {
                const int d = 16*j + l15;
                const float invf = expf(-(float)d * ROPE_C);
                float sn, cs;
                sincosf((float)s * invf, &sn, &cs);
                const float y1 = acc[j][r]*cs - acc[j+4][r]*sn;
                const float y2 = acc[j+4][r]*cs + acc[j][r]*sn;
                crow[d]      = y1;
                crow[d + 64] = y2;
                kb[(size_t)row * HD + d]      = __float2bfloat16(y1);
                kb[(size_t)row * HD + d + 64] = __float2bfloat16(y2);
            }
        }
    }
}

// ---------- flash MFMA attention, 32x32x16 S^T formulation ----------
// Round-6: LDS-pipe fix. Wave owns 32 q-rows via mfma_f32_32x32x16_bf16 ->
// same 32 ds_read_b128/tile/wave now cover 2x q-rows (LDS read traffic per
// work halves) + 25% better MFMA FLOP/cyc. Block = 2 waves (64 q-rows),
// grid 1024 = 4 blocks/CU, 8 waves/CU, 32KB LDS/block.
// pi-permuted V key order (32x32 variant): slot (ks,k) -> physical key
// (ks>>1)*32 + 8*((ks&1)*2+((k&7)>>2)) + 4*(k>>3) + (k&3), so PV B-frags are
// the lane's OWN packed p values (zero shuffles). All LDS accesses are
// wave-contiguous 1KB -> conflict-free without swizzle.
__global__ __launch_bounds__(128) void attn_mfma(const bf16* __restrict__ qbuf,
                                                 const bf16* __restrict__ kb,
                                                 const bf16* __restrict__ vt,
                                                 bf16* __restrict__ attn_out) {
    __shared__ bf16 Ks[8192];   // 16KB: frag-chunked K tile (64 keys x 128 dims)
    __shared__ bf16 Vt[8192];   // 16KB: frag-chunked, pi-permuted V^T tile

    const int tid  = threadIdx.x;
    const int wave = tid >> 6;        // 0..1
    const int lane = tid & 63;
    const int l31  = lane & 31;
    const int h    = lane >> 5;       // k-half
    const int q0   = blockIdx.x * 64;
    const int hh   = blockIdx.y;      // head
    const int b    = blockIdx.z;

    const bf16* kbb = kb + (size_t)b * SEQ * HD;
    const bf16* vtb = vt + (size_t)b * HD * SEQ;

    // Q B-frags: qfr[c] = Q[qrow = q0+wave*32+l31][dims c*16 + h*8 .. +7]
    frag qfr[8];
    {
        const bf16* qrow = qbuf + ((size_t)(b * SEQ + q0 + wave * 32 + l31)) * HID + hh * HD;
#pragma unroll
        for (int c = 0; c < 8; ++c)
            qfr[c] = *reinterpret_cast<const frag*>(qrow + c * 16 + h * 8);
    }

    // staging decode (chunk id n = tid + i*128, 16B chunks, LDS write at n*16):
    // K chunk n: kt=n>>9, c=(n>>6)&7, l=(n>>1)&31, hs=n&1
    //            holds K[key=kt*32+l][dims c*16+hs*8 ..+7]
    // V chunk n: dt=n>>8, ks=(n>>6)&3, l=(n>>1)&31, hs=n&1
    //            holds V^T[dim=dt*32+l][keys kA..kA+3, kA+8..kA+11],
    //            kA = (ks>>1)*32 + (ks&1)*16 + hs*4
    int koff[8], voff[8];
#pragma unroll
    for (int i = 0; i < 8; ++i) {
        const int n  = tid + i * 128;
        const int kl = (n >> 1) & 31, khs = n & 1;
        const int key  = ((n >> 9) << 5) + kl;
        const int dimb = (((n >> 6) & 7) << 4) + (khs << 3);
        koff[i] = key * HD + dimb;
        const int ks  = (n >> 6) & 3;
        const int dim = ((n >> 8) << 5) + kl;
        const int kA  = ((ks >> 1) << 5) + ((ks & 1) << 4) + (khs << 2);
        voff[i] = dim * SEQ + kA;
    }
    const int rpos = (l31 * 2 + h) * 16;   // within-frag byte offset (contig 1KB/wave)

    f32x16 oacc[4];
#pragma unroll
    for (int dt = 0; dt < 4; ++dt)
#pragma unroll
        for (int r = 0; r < 16; ++r) oacc[dt][r] = 0.f;
    float mrow = -1e30f;
    float lrow = 0.f;
    const float scale = 0.088388347648318433f;   // 1/sqrt(128)

    for (int t0 = 0; t0 < SEQ; t0 += 64) {
        __syncthreads();
        {
            uint4 krg[8];
            const bf16* kt0 = kbb + (size_t)t0 * HD;
#pragma unroll
            for (int i = 0; i < 8; ++i)
                krg[i] = *reinterpret_cast<const uint4*>(kt0 + koff[i]);
#pragma unroll
            for (int i = 0; i < 8; ++i)
                *reinterpret_cast<uint4*>(reinterpret_cast<char*>(Ks) + (tid + i*128) * 16) = krg[i];
            uint4 vrg[8];
            const bf16* vt0 = vtb + t0;
#pragma unroll
            for (int i = 0; i < 8; ++i) {
                const uint2 a = *reinterpret_cast<const uint2*>(vt0 + voff[i]);
                const uint2 c = *reinterpret_cast<const uint2*>(vt0 + voff[i] + 8);
                vrg[i] = (uint4){a.x, a.y, c.x, c.y};
            }
#pragma unroll
            for (int i = 0; i < 8; ++i)
                *reinterpret_cast<uint4*>(reinterpret_cast<char*>(Vt) + (tid + i*128) * 16) = vrg[i];
        }
        __syncthreads();

        // S^T: sacc[kt] rows = keys kt*32 + (reg&3)+8*(reg>>2)+4h, col = qrow l31
        f32x16 sacc[2];
#pragma unroll
        for (int kt = 0; kt < 2; ++kt)
#pragma unroll
            for (int r = 0; r < 16; ++r) sacc[kt][r] = 0.f;
#pragma unroll
        for (int c = 0; c < 8; ++c) {
            const frag kf0 = *reinterpret_cast<const frag*>(
                reinterpret_cast<const char*>(Ks) + (0*8 + c) * 1024 + rpos);
            const frag kf1 = *reinterpret_cast<const frag*>(
                reinterpret_cast<const char*>(Ks) + (1*8 + c) * 1024 + rpos);
            sacc[0] = __builtin_amdgcn_mfma_f32_32x32x16_bf16(kf0, qfr[c], sacc[0], 0, 0, 0);
            sacc[1] = __builtin_amdgcn_mfma_f32_32x32x16_bf16(kf1, qfr[c], sacc[1], 0, 0, 0);
        }

        // online softmax for qrow = l31 (partner half via xor-32)
        float mx = -1e30f;
#pragma unroll
        for (int kt = 0; kt < 2; ++kt)
#pragma unroll
            for (int r = 0; r < 16; ++r) mx = fmaxf(mx, sacc[kt][r]);
        mx = fmaxf(mx, __shfl_xor(mx, 32));
        const bool skip = (bool)__all(mx - mrow <= 90.0f);   // e^(90*scale) ~ e^8
        const float mn = skip ? mrow : fmaxf(mrow, mx);
        const float al = skip ? 1.f : __expf((mrow - mn) * scale);
        float p[2][16];
        float ps = 0.f;
#pragma unroll
        for (int kt = 0; kt < 2; ++kt)
#pragma unroll
            for (int r = 0; r < 16; ++r) {
                p[kt][r] = __expf((sacc[kt][r] - mn) * scale);
                ps += p[kt][r];
            }
        ps += __shfl_xor(ps, 32);
        lrow = lrow * al + ps;
        mrow = mn;

        // PV B-frags: pb[ks] elem j = p[ks>>1][((ks&1)*2 + (j>>2))*4 + (j&3)]
        frag pb[4];
#pragma unroll
        for (int ks = 0; ks < 4; ++ks) {
            const int kt = ks >> 1, ta = (ks & 1) * 2, tb = ta + 1;
            union { unsigned u[4]; frag f; } pf;
            pf.u[0] = pk2(p[kt][ta*4+0], p[kt][ta*4+1]);
            pf.u[1] = pk2(p[kt][ta*4+2], p[kt][ta*4+3]);
            pf.u[2] = pk2(p[kt][tb*4+0], p[kt][tb*4+1]);
            pf.u[3] = pk2(p[kt][tb*4+2], p[kt][tb*4+3]);
            pb[ks] = pf.f;
        }

        // rescale O accumulators (skipped when max growth deferred)
        if (!skip)
#pragma unroll
            for (int dt = 0; dt < 4; ++dt)
#pragma unroll
                for (int r = 0; r < 16; ++r) oacc[dt][r] *= al;

        // O^T += V^T P^T
#pragma unroll
        for (int dt = 0; dt < 4; ++dt) {
#pragma unroll
            for (int ks = 0; ks < 4; ++ks) {
                const frag vf = *reinterpret_cast<const frag*>(
                    reinterpret_cast<const char*>(Vt) + (dt*4 + ks) * 1024 + rpos);
                oacc[dt] = __builtin_amdgcn_mfma_f32_32x32x16_bf16(vf, pb[ks], oacc[dt], 0, 0, 0);
            }
        }
    }

    // epilogue: lane holds O[qrow=l31][dim = dt*32 + 8t + 4h + r]
    {
        const float inv = 1.f / lrow;
        const int s = q0 + wave * 32 + l31;
        bf16* orow = attn_out + ((size_t)(b * SEQ + s)) * HID + hh * HD;
#pragma unroll
        for (int dt = 0; dt < 4; ++dt)
#pragma unroll
            for (int t = 0; t < 4; ++t) {
                uint2 val;
                val.x = pk2(oacc[dt][t*4+0] * inv, oacc[dt][t*4+1] * inv);
                val.y = pk2(oacc[dt][t*4+2] * inv, oacc[dt][t*4+3] * inv);
                *reinterpret_cast<uint2*>(orow + dt*32 + t*8 + h*4) = val;
            }
    }
}

// ---------- final projection, 8-wave 128x128 tiles (unchanged, passing) ----------
__global__ __launch_bounds__(512) void gemm_o_mfma(const bf16* __restrict__ A,
                                                   const float* __restrict__ W,
                                                   float* __restrict__ C) {
    __shared__ bf16 Asl[4096];
    __shared__ bf16 Bsl[4096];
    const int tid  = threadIdx.x;
    const int wave = tid >> 6;
    const int lane = tid & 63;
    const int quad = lane >> 4;
    const int l15  = lane & 15;
    const int row0 = blockIdx.y * 128;
    const int col0 = blockIdx.x * 128;

    const int sr = tid >> 2;
    const int sc = (tid & 3) * 8;

    f32x4 acc[8];
#pragma unroll
    for (int j = 0; j < 8; ++j) acc[j] = (f32x4){0.f,0.f,0.f,0.f};

    for (int k0 = 0; k0 < HID; k0 += 32) {
        __syncthreads();
        {
            *reinterpret_cast<uint4*>(&Asl[tid * 8]) =
                *reinterpret_cast<const uint4*>(A + (size_t)(row0 + sr) * HID + k0 + sc);
            const float4* b0 = reinterpret_cast<const float4*>(W + (size_t)(col0 + sr) * HID + k0 + sc);
            cvt8_store(b0[0], b0[1], &Bsl[tid * 8]);
        }
        __syncthreads();
        frag af, bfr[8];
        af = *reinterpret_cast<const frag*>(&Asl[(((wave*16 + l15)*4) + quad) * 8]);
#pragma unroll
        for (int j = 0; j < 8; ++j)
            bfr[j] = *reinterpret_cast<const frag*>(&Bsl[(((j*16 + l15)*4) + quad) * 8]);
#pragma unroll
        for (int j = 0; j < 8; ++j)
            acc[j] = __builtin_amdgcn_mfma_f32_16x16x32_bf16(af, bfr[j], acc[j], 0, 0, 0);
    }

#pragma unroll
    for (int r = 0; r < 4; ++r) {
        const int row = row0 + wave*16 + quad*4 + r;
        float* crow = C + (size_t)row * HID + col0;
#pragma unroll
        for (int j = 0; j < 8; ++j)
            crow[16*j + l15] = acc[j][r];
    }
}

// ---------- launch ----------
extern "C" void kernel_launch(void* const* d_in, const int* in_sizes, int n_in,
                              void* d_out, int out_size, void* d_ws, size_t ws_size,
                              hipStream_t stream) {
    const float* hs = (const float*)d_in[0];
    const float* Wq = (const float*)d_in[1];
    const float* Wk = (const float*)d_in[2];
    const float* Wv = (const float*)d_in[3];
    const float* Wo = (const float*)d_in[4];

    float* out      = (float*)d_out;
    float* out_attn = out;                         // [B,S,H]    8388608 f32 (33.55 MB)
    float* out_k    = out + 8388608;               // [B,1,S,HD]  524288 f32
    float* out_v    = out + 8388608 + 524288;      // [B,1,S,HD]  524288 f32

    // Scratch inside d_out's attn region (consumed before gemm_o_mfma writes it):
    bf16* qbuf = (bf16*)d_out;                     // bytes 0..16.78M  roped q bf16
    bf16* kb   = (bf16*)((char*)d_out + 16777216); // bytes ..17.83M   roped k bf16
    bf16* vt   = (bf16*)((char*)d_out + 17825792); // bytes ..18.87M   v^T bf16
    bf16* attn_out = (bf16*)d_ws;                  // [B,S,H] bf16, 16.78 MB

    gemm_qkv  <<<dim3(18, (BB*SEQ)/128), dim3(512), 0, stream>>>(hs, Wq, Wk, Wv,
                                                                 qbuf, out_k, out_v, kb, vt);
    attn_mfma <<<dim3(SEQ/64, NH, BB),   dim3(128), 0, stream>>>(qbuf, kb, vt, attn_out);
    gemm_o_mfma<<<dim3(HID/128, (BB*SEQ)/128), dim3(512), 0, stream>>>(attn_out, Wo, out_attn);
}

// Round 7
// 391.979 us; speedup vs baseline: 1.1069x; 1.1069x over previous
//
#include <hip/hip_runtime.h>
#include <hip/hip_bf16.h>

typedef __hip_bfloat16 bf16;

#define NH   16
#define HD   128
#define SEQ  2048
#define BB   2
#define HID  2048

// ln(10000)/64
#define ROPE_C 0.14391156856f

using frag   = __attribute__((ext_vector_type(8))) short;   // 8 bf16 = 4 VGPRs
using f32x4  = __attribute__((ext_vector_type(4))) float;
using f32x16 = __attribute__((ext_vector_type(16))) float;

// ---------- helpers ----------

// pack 8 fp32 -> 8 bf16 (one 16B LDS write)
__device__ __forceinline__ void cvt8_store(const float4 f0, const float4 f1, bf16* dst) {
    union { frag v; bf16 h[8]; } p;
    p.h[0] = __float2bfloat16(f0.x); p.h[1] = __float2bfloat16(f0.y);
    p.h[2] = __float2bfloat16(f0.z); p.h[3] = __float2bfloat16(f0.w);
    p.h[4] = __float2bfloat16(f1.x); p.h[5] = __float2bfloat16(f1.y);
    p.h[6] = __float2bfloat16(f1.z); p.h[7] = __float2bfloat16(f1.w);
    *reinterpret_cast<frag*>(dst) = p.v;
}

// pack 2 fp32 -> 1 dword of 2 bf16
__device__ __forceinline__ unsigned pk2(float a, float b) {
    union { bf16 h[2]; unsigned u; } p;
    p.h[0] = __float2bfloat16(a);
    p.h[1] = __float2bfloat16(b);
    return p.u;
}

// ---------- fused Q/K/V projection, 8-wave 128x128 tiles (unchanged, passing) ----------
__global__ __launch_bounds__(512) void gemm_qkv(const float* __restrict__ A,
                                                const float* __restrict__ Wq,
                                                const float* __restrict__ Wk,
                                                const float* __restrict__ Wv,
                                                bf16* __restrict__ qout,
                                                float* __restrict__ Ck,
                                                float* __restrict__ Cv,
                                                bf16* __restrict__ kb,
                                                bf16* __restrict__ vt) {
    __shared__ bf16 Asl[4096];   // 128 rows x 32 k (bf16)
    __shared__ bf16 Bsl[4096];
    const int tid  = threadIdx.x;
    const int wave = tid >> 6;
    const int lane = tid & 63;
    const int quad = lane >> 4;
    const int l15  = lane & 15;
    const int row0 = blockIdx.y * 128;
    const int bx   = blockIdx.x;
    const bool isq  = bx < 16;
    const bool is_v = (bx == 17);
    const float* W  = isq ? Wq : (is_v ? Wv : Wk);
    const int col0  = isq ? bx * 128 : 0;

    const int sr = tid >> 2;          // 0..127
    const int sc = (tid & 3) * 8;     // 0,8,16,24

    f32x4 acc[8];
#pragma unroll
    for (int j = 0; j < 8; ++j) acc[j] = (f32x4){0.f,0.f,0.f,0.f};

    for (int k0 = 0; k0 < HID; k0 += 32) {
        __syncthreads();
        {
            const float4* a0 = reinterpret_cast<const float4*>(A + (size_t)(row0 + sr) * HID + k0 + sc);
            const float4* b0 = reinterpret_cast<const float4*>(W + (size_t)(col0 + sr) * HID + k0 + sc);
            cvt8_store(a0[0], a0[1], &Asl[tid * 8]);
            cvt8_store(b0[0], b0[1], &Bsl[tid * 8]);
        }
        __syncthreads();
        frag af, bfr[8];
        af = *reinterpret_cast<const frag*>(&Asl[(((wave*16 + l15)*4) + quad) * 8]);
#pragma unroll
        for (int j = 0; j < 8; ++j)
            bfr[j] = *reinterpret_cast<const frag*>(&Bsl[(((j*16 + l15)*4) + quad) * 8]);
#pragma unroll
        for (int j = 0; j < 8; ++j)
            acc[j] = __builtin_amdgcn_mfma_f32_16x16x32_bf16(af, bfr[j], acc[j], 0, 0, 0);
    }

    if (isq) {
#pragma unroll
        for (int r = 0; r < 4; ++r) {
            const int row = row0 + wave*16 + quad*4 + r;
            const int s = row & (SEQ - 1);
            bf16* crow = qout + (size_t)row * HID + col0;
#pragma unroll
            for (int j = 0; j < 4; ++j) {
                const int d = 16*j + l15;
                const float invf = expf(-(float)d * ROPE_C);
                float sn, cs;
                sincosf((float)s * invf, &sn, &cs);
                const float x1 = acc[j][r], x2 = acc[j+4][r];
                crow[d]      = __float2bfloat16(x1*cs - x2*sn);
                crow[d + 64] = __float2bfloat16(x2*cs + x1*sn);
            }
        }
    } else if (is_v) {
#pragma unroll
        for (int r = 0; r < 4; ++r) {
            const int row = row0 + wave*16 + quad*4 + r;   // b*SEQ + s
            const int s = row & (SEQ - 1);
            const int b = row >> 11;
            float* crow = Cv + (size_t)row * HD;
#pragma unroll
            for (int j = 0; j < 8; ++j) {
                const int d = 16*j + l15;
                const float val = acc[j][r];
                crow[d] = val;
                vt[((size_t)b * HD + d) * SEQ + s] = __float2bfloat16(val);
            }
        }
    } else {
#pragma unroll
        for (int r = 0; r < 4; ++r) {
            const int row = row0 + wave*16 + quad*4 + r;
            const int s = row & (SEQ - 1);
            float* crow = Ck + (size_t)row * HD;
#pragma unroll
            for (int j = 0; j < 4; ++j) {
                const int d = 16*j + l15;
                const float invf = expf(-(float)d * ROPE_C);
                float sn, cs;
                sincosf((float)s * invf, &sn, &cs);
                const float y1 = acc[j][r]*cs - acc[j+4][r]*sn;
                const float y2 = acc[j+4][r]*cs + acc[j][r]*sn;
                crow[d]      = y1;
                crow[d + 64] = y2;
                kb[(size_t)row * HD + d]      = __float2bfloat16(y1);
                kb[(size_t)row * HD + d + 64] = __float2bfloat16(y2);
            }
        }
    }
}

// ---------- flash MFMA attention, 32x32x16, 4-wave key-split blocks ----------
// Round-7: waves = (qg,kg). Wave (qg,kg): q-rows qg*32..+31, keys it*64+kg*32.
// Each kg pair has its own LDS half (K: kg*8KB in [0,16K); V: 16K + kg*8KB).
// Two-term XOR swizzle B ^= (((B>>7)^(B>>10))&7)<<4 : spreads both frag reads
// (l31-stride-128 pathology, round-6's 8.4M conflicts) and staging writes
// (1024B-stride chunks). Read side folds to per-chunk constant (rsw ^ cb<<4).
// pi-permuted PV key order degenerates to pb[ks] elem j = p[8ks+j] (0 shuffles).
// Final flash-decoding merge across kg via padded LDS exchange (4 rounds).
__global__ __launch_bounds__(256) void attn_mfma(const bf16* __restrict__ qbuf,
                                                 const bf16* __restrict__ kb,
                                                 const bf16* __restrict__ vt,
                                                 bf16* __restrict__ attn_out) {
    __shared__ char lds[32768];

    const int tid  = threadIdx.x;
    const int wave = tid >> 6;
    const int lane = tid & 63;
    const int l31  = lane & 31;
    const int h    = lane >> 5;
    const int qg   = wave & 1;
    const int kg   = wave >> 1;
    const int q0   = blockIdx.x * 64;
    const int hh   = blockIdx.y;      // head
    const int b    = blockIdx.z;

    const bf16* kbb = kb + (size_t)b * SEQ * HD;
    const bf16* vtb = vt + (size_t)b * HD * SEQ;

    // Q B-frags: qfr[c] = Q[qrow = q0+qg*32+l31][dims c*16 + h*8 .. +7]
    frag qfr[8];
    {
        const bf16* qrow = qbuf + ((size_t)(b * SEQ + q0 + qg * 32 + l31)) * HID + hh * HD;
#pragma unroll
        for (int c = 0; c < 8; ++c)
            qfr[c] = *reinterpret_cast<const frag*>(qrow + c * 16 + h * 8);
    }

    // staging: 128 threads (sl) per kg_s half
    const int sl   = tid & 127;
    const int kg_s = tid >> 7;

    // K: 4 x 16B chunks, global-contiguous n = sl + i*128 (global elem = 8n)
    //    n -> key=n>>4, d=(n>>1)&7, hs=n&1 ; LDS L = d*64 + key*2 + hs
    int klof[4];
#pragma unroll
    for (int i = 0; i < 4; ++i) {
        const int n   = sl + i * 128;
        const int key = n >> 4, d = (n >> 1) & 7, hs = n & 1;
        const int L   = d * 64 + key * 2 + hs;
        klof[i] = (kg_s * 8192 + L * 16) ^ (((((key >> 2) ^ d) & 7)) << 4);
    }
    // V: 8 x 8B granules g = sl + i*128: dim=g>>3, ks=(g>>2)&1, m=(g>>1)&1, hs=g&1
    int vlof[8], vgof[8];
#pragma unroll
    for (int i = 0; i < 8; ++i) {
        const int g   = sl + i * 128;
        const int dim = g >> 3, ks = (g >> 2) & 1, m = (g >> 1) & 1, hs = g & 1;
        const int dt  = dim >> 5;
        const int C   = (dt * 2 + ks) * 64 + (dim & 31) * 2 + hs;
        const int B   = 16384 + kg_s * 8192 + C * 16 + m * 8;
        const int xv  = (((dim & 31) >> 2) ^ (dt * 2 + ks)) & 7;
        vlof[i] = B ^ (xv << 4);
        vgof[i] = dim * SEQ + kg_s * 32 + (g & 7) * 4;
    }

    // frag-read base: within-chunk byte (l31*2+h)*16, swizzled (>>7 term);
    // per-chunk (>>10) term applied as compile-time (cb<<4) XOR at use site.
    const int rpos = (l31 * 2 + h) * 16;
    const int rsw  = rpos ^ ((((rpos >> 7) & 7)) << 4);

    f32x16 oacc[4];
#pragma unroll
    for (int dt = 0; dt < 4; ++dt)
#pragma unroll
        for (int r = 0; r < 16; ++r) oacc[dt][r] = 0.f;
    float mrow = -1e30f;
    float lrow = 0.f;
    const float scale = 0.088388347648318433f;   // 1/sqrt(128)

    for (int it = 0; it < SEQ / 64; ++it) {
        __syncthreads();
        {
            const bf16* kp = kbb + (size_t)it * 64 * HD + kg_s * 4096;
            const bf16* vp = vtb + it * 64;
            uint4 krg[4];
            uint2 vrg[8];
#pragma unroll
            for (int i = 0; i < 4; ++i)
                krg[i] = *reinterpret_cast<const uint4*>(kp + (sl + i * 128) * 8);
#pragma unroll
            for (int i = 0; i < 8; ++i)
                vrg[i] = *reinterpret_cast<const uint2*>(vp + vgof[i]);
#pragma unroll
            for (int i = 0; i < 4; ++i)
                *reinterpret_cast<uint4*>(lds + klof[i]) = krg[i];
#pragma unroll
            for (int i = 0; i < 8; ++i)
                *reinterpret_cast<uint2*>(lds + vlof[i]) = vrg[i];
        }
        __syncthreads();

        // S^T (32 keys x 32 qrows): rows = keys (r&3)+8*(r>>2)+4h, col = l31
        f32x16 sacc;
#pragma unroll
        for (int r = 0; r < 16; ++r) sacc[r] = 0.f;
#pragma unroll
        for (int c = 0; c < 8; ++c) {
            const frag kf = *reinterpret_cast<const frag*>(
                lds + kg * 8192 + c * 1024 + (rsw ^ (c << 4)));
            sacc = __builtin_amdgcn_mfma_f32_32x32x16_bf16(kf, qfr[c], sacc, 0, 0, 0);
        }

        // online softmax for qrow = l31 (partner h via xor-32)
        float mx = -1e30f;
#pragma unroll
        for (int r = 0; r < 16; ++r) mx = fmaxf(mx, sacc[r]);
        mx = fmaxf(mx, __shfl_xor(mx, 32));
        const bool skip = (bool)__all(mx - mrow <= 90.0f);   // e^(90*scale) ~ e^8
        const float mn = skip ? mrow : fmaxf(mrow, mx);
        const float al = skip ? 1.f : __expf((mrow - mn) * scale);
        float p[16];
        float ps = 0.f;
#pragma unroll
        for (int r = 0; r < 16; ++r) {
            p[r] = __expf((sacc[r] - mn) * scale);
            ps += p[r];
        }
        ps += __shfl_xor(ps, 32);
        lrow = lrow * al + ps;
        mrow = mn;

        // PV B-frags: pb[ks] elem j = p[8ks+j] (pi-permuted V key order)
        frag pb[2];
#pragma unroll
        for (int ks = 0; ks < 2; ++ks) {
            union { unsigned u[4]; frag f; } pf;
#pragma unroll
            for (int w = 0; w < 4; ++w)
                pf.u[w] = pk2(p[8 * ks + 2 * w], p[8 * ks + 2 * w + 1]);
            pb[ks] = pf.f;
        }

        if (!skip)
#pragma unroll
            for (int dt = 0; dt < 4; ++dt)
#pragma unroll
                for (int r = 0; r < 16; ++r) oacc[dt][r] *= al;

        // O^T += V^T P^T
#pragma unroll
        for (int dt = 0; dt < 4; ++dt)
#pragma unroll
            for (int ks = 0; ks < 2; ++ks) {
                const int cb = dt * 2 + ks;
                const frag vf = *reinterpret_cast<const frag*>(
                    lds + 16384 + kg * 8192 + cb * 1024 + (rsw ^ (cb << 4)));
                oacc[dt] = __builtin_amdgcn_mfma_f32_32x32x16_bf16(vf, pb[ks], oacc[dt], 0, 0, 0);
            }
    }

    // ---- flash-decoding merge across kg pairs ----
    __syncthreads();
    float* fl = reinterpret_cast<float*>(lds);
    if (h == 0) {
        fl[(qg * 2 + kg) * 32 + l31]       = mrow;
        fl[128 + (qg * 2 + kg) * 32 + l31] = lrow;
    }
    __syncthreads();
    const float m0 = fl[qg * 64 + l31],       m1 = fl[qg * 64 + 32 + l31];
    const float l0 = fl[128 + qg * 64 + l31], l1 = fl[128 + qg * 64 + 32 + l31];
    const float ms = fmaxf(m0, m1);
    const float c0 = __expf((m0 - ms) * scale);
    const float c1 = __expf((m1 - ms) * scale);
    const float inv = 1.f / (c0 * l0 + c1 * l1);
    const float cs = kg ? c1 : c0;
#pragma unroll
    for (int dt = 0; dt < 4; ++dt)
#pragma unroll
        for (int r = 0; r < 16; ++r) oacc[dt][r] *= cs;

    float* ob = reinterpret_cast<float*>(lds + 1024);   // [qg*64+lane][17] padded
#pragma unroll
    for (int dt = 0; dt < 4; ++dt) {
        __syncthreads();
        if (kg == 1) {
            float* dst = ob + (qg * 64 + lane) * 17;
#pragma unroll
            for (int r = 0; r < 16; ++r) dst[r] = oacc[dt][r];
        }
        __syncthreads();
        if (kg == 0) {
            const float* sp = ob + (qg * 64 + lane) * 17;
            const int s = q0 + qg * 32 + l31;
            bf16* orow = attn_out + ((size_t)(b * SEQ + s)) * HID + hh * HD;
#pragma unroll
            for (int t = 0; t < 4; ++t) {
                const float v0 = (oacc[dt][t*4+0] + sp[t*4+0]) * inv;
                const float v1 = (oacc[dt][t*4+1] + sp[t*4+1]) * inv;
                const float v2 = (oacc[dt][t*4+2] + sp[t*4+2]) * inv;
                const float v3 = (oacc[dt][t*4+3] + sp[t*4+3]) * inv;
                uint2 val;
                val.x = pk2(v0, v1);
                val.y = pk2(v2, v3);
                *reinterpret_cast<uint2*>(orow + dt * 32 + t * 8 + h * 4) = val;
            }
        }
    }
}

// ---------- final projection, 8-wave 128x128 tiles (unchanged, passing) ----------
__global__ __launch_bounds__(512) void gemm_o_mfma(const bf16* __restrict__ A,
                                                   const float* __restrict__ W,
                                                   float* __restrict__ C) {
    __shared__ bf16 Asl[4096];
    __shared__ bf16 Bsl[4096];
    const int tid  = threadIdx.x;
    const int wave = tid >> 6;
    const int lane = tid & 63;
    const int quad = lane >> 4;
    const int l15  = lane & 15;
    const int row0 = blockIdx.y * 128;
    const int col0 = blockIdx.x * 128;

    const int sr = tid >> 2;
    const int sc = (tid & 3) * 8;

    f32x4 acc[8];
#pragma unroll
    for (int j = 0; j < 8; ++j) acc[j] = (f32x4){0.f,0.f,0.f,0.f};

    for (int k0 = 0; k0 < HID; k0 += 32) {
        __syncthreads();
        {
            *reinterpret_cast<uint4*>(&Asl[tid * 8]) =
                *reinterpret_cast<const uint4*>(A + (size_t)(row0 + sr) * HID + k0 + sc);
            const float4* b0 = reinterpret_cast<const float4*>(W + (size_t)(col0 + sr) * HID + k0 + sc);
            cvt8_store(b0[0], b0[1], &Bsl[tid * 8]);
        }
        __syncthreads();
        frag af, bfr[8];
        af = *reinterpret_cast<const frag*>(&Asl[(((wave*16 + l15)*4) + quad) * 8]);
#pragma unroll
        for (int j = 0; j < 8; ++j)
            bfr[j] = *reinterpret_cast<const frag*>(&Bsl[(((j*16 + l15)*4) + quad) * 8]);
#pragma unroll
        for (int j = 0; j < 8; ++j)
            acc[j] = __builtin_amdgcn_mfma_f32_16x16x32_bf16(af, bfr[j], acc[j], 0, 0, 0);
    }

#pragma unroll
    for (int r = 0; r < 4; ++r) {
        const int row = row0 + wave*16 + quad*4 + r;
        float* crow = C + (size_t)row * HID + col0;
#pragma unroll
        for (int j = 0; j < 8; ++j)
            crow[16*j + l15] = acc[j][r];
    }
}

// ---------- launch ----------
extern "C" void kernel_launch(void* const* d_in, const int* in_sizes, int n_in,
                              void* d_out, int out_size, void* d_ws, size_t ws_size,
                              hipStream_t stream) {
    const float* hs = (const float*)d_in[0];
    const float* Wq = (const float*)d_in[1];
    const float* Wk = (const float*)d_in[2];
    const float* Wv = (const float*)d_in[3];
    const float* Wo = (const float*)d_in[4];

    float* out      = (float*)d_out;
    float* out_attn = out;                         // [B,S,H]    8388608 f32 (33.55 MB)
    float* out_k    = out + 8388608;               // [B,1,S,HD]  524288 f32
    float* out_v    = out + 8388608 + 524288;      // [B,1,S,HD]  524288 f32

    // Scratch inside d_out's attn region (consumed before gemm_o_mfma writes it):
    bf16* qbuf = (bf16*)d_out;                     // bytes 0..16.78M  roped q bf16
    bf16* kb   = (bf16*)((char*)d_out + 16777216); // bytes ..17.83M   roped k bf16
    bf16* vt   = (bf16*)((char*)d_out + 17825792); // bytes ..18.87M   v^T bf16
    bf16* attn_out = (bf16*)d_ws;                  // [B,S,H] bf16, 16.78 MB

    gemm_qkv  <<<dim3(18, (BB*SEQ)/128), dim3(512), 0, stream>>>(hs, Wq, Wk, Wv,
                                                                 qbuf, out_k, out_v, kb, vt);
    attn_mfma <<<dim3(SEQ/64, NH, BB),   dim3(256), 0, stream>>>(qbuf, kb, vt, attn_out);
    gemm_o_mfma<<<dim3(HID/128, (BB*SEQ)/128), dim3(512), 0, stream>>>(attn_out, Wo, out_attn);
}

// Round 8
// 377.695 us; speedup vs baseline: 1.1488x; 1.0378x over previous
//
#include <hip/hip_runtime.h>
#include <hip/hip_bf16.h>

typedef __hip_bfloat16 bf16;

#define NH   16
#define HD   128
#define SEQ  2048
#define BB   2
#define HID  2048

// ln(10000)/64
#define ROPE_C 0.14391156856f

using frag   = __attribute__((ext_vector_type(8))) short;   // 8 bf16 = 4 VGPRs
using f32x4  = __attribute__((ext_vector_type(4))) float;
using f32x16 = __attribute__((ext_vector_type(16))) float;

// ---------- helpers ----------

// pack 8 fp32 -> 8 bf16 (one 16B LDS write)
__device__ __forceinline__ void cvt8_store(const float4 f0, const float4 f1, bf16* dst) {
    union { frag v; bf16 h[8]; } p;
    p.h[0] = __float2bfloat16(f0.x); p.h[1] = __float2bfloat16(f0.y);
    p.h[2] = __float2bfloat16(f0.z); p.h[3] = __float2bfloat16(f0.w);
    p.h[4] = __float2bfloat16(f1.x); p.h[5] = __float2bfloat16(f1.y);
    p.h[6] = __float2bfloat16(f1.z); p.h[7] = __float2bfloat16(f1.w);
    *reinterpret_cast<frag*>(dst) = p.v;
}

// pack 2 fp32 -> 1 dword of 2 bf16
__device__ __forceinline__ unsigned pk2(float a, float b) {
    union { bf16 h[2]; unsigned u; } p;
    p.h[0] = __float2bfloat16(a);
    p.h[1] = __float2bfloat16(b);
    return p.u;
}

// async global->LDS, 16B per lane (dest = wave-uniform base + lane*16)
__device__ __forceinline__ void gld_lds16(const bf16* g, bf16* l) {
    __builtin_amdgcn_global_load_lds(
        (const __attribute__((address_space(1))) void*)g,
        (__attribute__((address_space(3))) void*)l, 16, 0, 0);
}

// ---------- prepass: fp32 -> bf16 for hs, Wq, Wk, Wv ----------
// 2048 f32 per block (256 thr x 8). hs:4096 blocks, Wq:2048, Wk:128, Wv:128.
__global__ __launch_bounds__(256) void cvt_bf16(const float* __restrict__ hs,
                                                const float* __restrict__ Wq,
                                                const float* __restrict__ Wk,
                                                const float* __restrict__ Wv,
                                                bf16* __restrict__ hsb,
                                                bf16* __restrict__ wqb,
                                                bf16* __restrict__ wkb,
                                                bf16* __restrict__ wvb) {
    const int blk = blockIdx.x;
    const float* src;
    bf16* dst;
    if (blk < 4096)      { src = hs + (size_t)blk * 2048;          dst = hsb + (size_t)blk * 2048; }
    else if (blk < 6144) { src = Wq + (size_t)(blk - 4096) * 2048; dst = wqb + (size_t)(blk - 4096) * 2048; }
    else if (blk < 6272) { src = Wk + (size_t)(blk - 6144) * 2048; dst = wkb + (size_t)(blk - 6144) * 2048; }
    else                 { src = Wv + (size_t)(blk - 6272) * 2048; dst = wvb + (size_t)(blk - 6272) * 2048; }
    const int t = threadIdx.x * 8;
    const float4 f0 = *reinterpret_cast<const float4*>(src + t);
    const float4 f1 = *reinterpret_cast<const float4*>(src + t + 4);
    cvt8_store(f0, f1, dst + t);
}

// ---------- fused Q/K/V projection, 8-wave 128x128 tiles, all-bf16 + global_load_lds ----------
// grid (18, 32): x<16 -> Q col-tile x (RoPE); x==16 -> K; x==17 -> V.
// Staging is pure async DMA: 2 x global_load_lds(16B) per thread per k-step,
// zero VALU, no register roundtrip (m93->m97 lever, +69% on this structure).
__global__ __launch_bounds__(512) void gemm_qkv(const bf16* __restrict__ A,
                                                const bf16* __restrict__ Wqb,
                                                const bf16* __restrict__ Wkb,
                                                const bf16* __restrict__ Wvb,
                                                bf16* __restrict__ qout,
                                                float* __restrict__ Ck,
                                                float* __restrict__ Cv,
                                                bf16* __restrict__ kb,
                                                bf16* __restrict__ vt) {
    __shared__ bf16 Asl[4096];   // 128 rows x 32 k (bf16), chunk n at byte n*16
    __shared__ bf16 Bsl[4096];
    const int tid  = threadIdx.x;
    const int wave = tid >> 6;
    const int lane = tid & 63;
    const int quad = lane >> 4;
    const int l15  = lane & 15;
    const int row0 = blockIdx.y * 128;
    const int bx   = blockIdx.x;
    const bool isq  = bx < 16;
    const bool is_v = (bx == 17);
    const bf16* W   = isq ? Wqb : (is_v ? Wvb : Wkb);
    const int col0  = isq ? bx * 128 : 0;

    const int sr = tid >> 2;          // 0..127
    const int sc = (tid & 3) * 8;     // 0,8,16,24

    const bf16* ag = A + (size_t)(row0 + sr) * HID + sc;
    const bf16* bg = W + (size_t)(col0 + sr) * HID + sc;
    bf16* al = &Asl[tid * 8];
    bf16* bl = &Bsl[tid * 8];

    f32x4 acc[8];
#pragma unroll
    for (int j = 0; j < 8; ++j) acc[j] = (f32x4){0.f,0.f,0.f,0.f};

    for (int k0 = 0; k0 < HID; k0 += 32) {
        __syncthreads();
        gld_lds16(ag + k0, al);
        gld_lds16(bg + k0, bl);
        __syncthreads();
        frag af, bfr[8];
        af = *reinterpret_cast<const frag*>(&Asl[(((wave*16 + l15)*4) + quad) * 8]);
#pragma unroll
        for (int j = 0; j < 8; ++j)
            bfr[j] = *reinterpret_cast<const frag*>(&Bsl[(((j*16 + l15)*4) + quad) * 8]);
#pragma unroll
        for (int j = 0; j < 8; ++j)
            acc[j] = __builtin_amdgcn_mfma_f32_16x16x32_bf16(af, bfr[j], acc[j], 0, 0, 0);
    }

    if (isq) {
#pragma unroll
        for (int r = 0; r < 4; ++r) {
            const int row = row0 + wave*16 + quad*4 + r;
            const int s = row & (SEQ - 1);
            bf16* crow = qout + (size_t)row * HID + col0;
#pragma unroll
            for (int j = 0; j < 4; ++j) {
                const int d = 16*j + l15;
                const float invf = expf(-(float)d * ROPE_C);
                float sn, cs;
                sincosf((float)s * invf, &sn, &cs);
                const float x1 = acc[j][r], x2 = acc[j+4][r];
                crow[d]      = __float2bfloat16(x1*cs - x2*sn);
                crow[d + 64] = __float2bfloat16(x2*cs + x1*sn);
            }
        }
    } else if (is_v) {
#pragma unroll
        for (int r = 0; r < 4; ++r) {
            const int row = row0 + wave*16 + quad*4 + r;   // b*SEQ + s
            const int s = row & (SEQ - 1);
            const int b = row >> 11;
            float* crow = Cv + (size_t)row * HD;
#pragma unroll
            for (int j = 0; j < 8; ++j) {
                const int d = 16*j + l15;
                const float val = acc[j][r];
                crow[d] = val;
                vt[((size_t)b * HD + d) * SEQ + s] = __float2bfloat16(val);
            }
        }
    } else {
#pragma unroll
        for (int r = 0; r < 4; ++r) {
            const int row = row0 + wave*16 + quad*4 + r;
            const int s = row & (SEQ - 1);
            float* crow = Ck + (size_t)row * HD;
#pragma unroll
            for (int j = 0; j < 4; ++j) {
                const int d = 16*j + l15;
                const float invf = expf(-(float)d * ROPE_C);
                float sn, cs;
                sincosf((float)s * invf, &sn, &cs);
                const float y1 = acc[j][r]*cs - acc[j+4][r]*sn;
                const float y2 = acc[j+4][r]*cs + acc[j][r]*sn;
                crow[d]      = y1;
                crow[d + 64] = y2;
                kb[(size_t)row * HD + d]      = __float2bfloat16(y1);
                kb[(size_t)row * HD + d + 64] = __float2bfloat16(y2);
            }
        }
    }
}

// ---------- flash MFMA attention, 32x32x16, 4-wave key-split blocks (unchanged, passing) ----------
__global__ __launch_bounds__(256) void attn_mfma(const bf16* __restrict__ qbuf,
                                                 const bf16* __restrict__ kb,
                                                 const bf16* __restrict__ vt,
                                                 bf16* __restrict__ attn_out) {
    __shared__ char lds[32768];

    const int tid  = threadIdx.x;
    const int wave = tid >> 6;
    const int lane = tid & 63;
    const int l31  = lane & 31;
    const int h    = lane >> 5;
    const int qg   = wave & 1;
    const int kg   = wave >> 1;
    const int q0   = blockIdx.x * 64;
    const int hh   = blockIdx.y;      // head
    const int b    = blockIdx.z;

    const bf16* kbb = kb + (size_t)b * SEQ * HD;
    const bf16* vtb = vt + (size_t)b * HD * SEQ;

    // Q B-frags: qfr[c] = Q[qrow = q0+qg*32+l31][dims c*16 + h*8 .. +7]
    frag qfr[8];
    {
        const bf16* qrow = qbuf + ((size_t)(b * SEQ + q0 + qg * 32 + l31)) * HID + hh * HD;
#pragma unroll
        for (int c = 0; c < 8; ++c)
            qfr[c] = *reinterpret_cast<const frag*>(qrow + c * 16 + h * 8);
    }

    // staging: 128 threads (sl) per kg_s half
    const int sl   = tid & 127;
    const int kg_s = tid >> 7;

    // K: 4 x 16B chunks, global-contiguous n = sl + i*128 (global elem = 8n)
    //    n -> key=n>>4, d=(n>>1)&7, hs=n&1 ; LDS L = d*64 + key*2 + hs
    int klof[4];
#pragma unroll
    for (int i = 0; i < 4; ++i) {
        const int n   = sl + i * 128;
        const int key = n >> 4, d = (n >> 1) & 7, hs = n & 1;
        const int L   = d * 64 + key * 2 + hs;
        klof[i] = (kg_s * 8192 + L * 16) ^ (((((key >> 2) ^ d) & 7)) << 4);
    }
    // V: 8 x 8B granules g = sl + i*128: dim=g>>3, ks=(g>>2)&1, m=(g>>1)&1, hs=g&1
    int vlof[8], vgof[8];
#pragma unroll
    for (int i = 0; i < 8; ++i) {
        const int g   = sl + i * 128;
        const int dim = g >> 3, ks = (g >> 2) & 1, m = (g >> 1) & 1, hs = g & 1;
        const int dt  = dim >> 5;
        const int C   = (dt * 2 + ks) * 64 + (dim & 31) * 2 + hs;
        const int B   = 16384 + kg_s * 8192 + C * 16 + m * 8;
        const int xv  = (((dim & 31) >> 2) ^ (dt * 2 + ks)) & 7;
        vlof[i] = B ^ (xv << 4);
        vgof[i] = dim * SEQ + kg_s * 32 + (g & 7) * 4;
    }

    // frag-read base: within-chunk byte (l31*2+h)*16, swizzled (>>7 term);
    // per-chunk (>>10) term applied as compile-time (cb<<4) XOR at use site.
    const int rpos = (l31 * 2 + h) * 16;
    const int rsw  = rpos ^ ((((rpos >> 7) & 7)) << 4);

    f32x16 oacc[4];
#pragma unroll
    for (int dt = 0; dt < 4; ++dt)
#pragma unroll
        for (int r = 0; r < 16; ++r) oacc[dt][r] = 0.f;
    float mrow = -1e30f;
    float lrow = 0.f;
    const float scale = 0.088388347648318433f;   // 1/sqrt(128)

    for (int it = 0; it < SEQ / 64; ++it) {
        __syncthreads();
        {
            const bf16* kp = kbb + (size_t)it * 64 * HD + kg_s * 4096;
            const bf16* vp = vtb + it * 64;
            uint4 krg[4];
            uint2 vrg[8];
#pragma unroll
            for (int i = 0; i < 4; ++i)
                krg[i] = *reinterpret_cast<const uint4*>(kp + (sl + i * 128) * 8);
#pragma unroll
            for (int i = 0; i < 8; ++i)
                vrg[i] = *reinterpret_cast<const uint2*>(vp + vgof[i]);
#pragma unroll
            for (int i = 0; i < 4; ++i)
                *reinterpret_cast<uint4*>(lds + klof[i]) = krg[i];
#pragma unroll
            for (int i = 0; i < 8; ++i)
                *reinterpret_cast<uint2*>(lds + vlof[i]) = vrg[i];
        }
        __syncthreads();

        // S^T (32 keys x 32 qrows): rows = keys (r&3)+8*(r>>2)+4h, col = l31
        f32x16 sacc;
#pragma unroll
        for (int r = 0; r < 16; ++r) sacc[r] = 0.f;
#pragma unroll
        for (int c = 0; c < 8; ++c) {
            const frag kf = *reinterpret_cast<const frag*>(
                lds + kg * 8192 + c * 1024 + (rsw ^ (c << 4)));
            sacc = __builtin_amdgcn_mfma_f32_32x32x16_bf16(kf, qfr[c], sacc, 0, 0, 0);
        }

        // online softmax for qrow = l31 (partner h via xor-32)
        float mx = -1e30f;
#pragma unroll
        for (int r = 0; r < 16; ++r) mx = fmaxf(mx, sacc[r]);
        mx = fmaxf(mx, __shfl_xor(mx, 32));
        const bool skip = (bool)__all(mx - mrow <= 90.0f);   // e^(90*scale) ~ e^8
        const float mn = skip ? mrow : fmaxf(mrow, mx);
        const float al = skip ? 1.f : __expf((mrow - mn) * scale);
        float p[16];
        float ps = 0.f;
#pragma unroll
        for (int r = 0; r < 16; ++r) {
            p[r] = __expf((sacc[r] - mn) * scale);
            ps += p[r];
        }
        ps += __shfl_xor(ps, 32);
        lrow = lrow * al + ps;
        mrow = mn;

        // PV B-frags: pb[ks] elem j = p[8ks+j] (pi-permuted V key order)
        frag pb[2];
#pragma unroll
        for (int ks = 0; ks < 2; ++ks) {
            union { unsigned u[4]; frag f; } pf;
#pragma unroll
            for (int w = 0; w < 4; ++w)
                pf.u[w] = pk2(p[8 * ks + 2 * w], p[8 * ks + 2 * w + 1]);
            pb[ks] = pf.f;
        }

        if (!skip)
#pragma unroll
            for (int dt = 0; dt < 4; ++dt)
#pragma unroll
                for (int r = 0; r < 16; ++r) oacc[dt][r] *= al;

        // O^T += V^T P^T
#pragma unroll
        for (int dt = 0; dt < 4; ++dt)
#pragma unroll
            for (int ks = 0; ks < 2; ++ks) {
                const int cb = dt * 2 + ks;
                const frag vf = *reinterpret_cast<const frag*>(
                    lds + 16384 + kg * 8192 + cb * 1024 + (rsw ^ (cb << 4)));
                oacc[dt] = __builtin_amdgcn_mfma_f32_32x32x16_bf16(vf, pb[ks], oacc[dt], 0, 0, 0);
            }
    }

    // ---- flash-decoding merge across kg pairs ----
    __syncthreads();
    float* fl = reinterpret_cast<float*>(lds);
    if (h == 0) {
        fl[(qg * 2 + kg) * 32 + l31]       = mrow;
        fl[128 + (qg * 2 + kg) * 32 + l31] = lrow;
    }
    __syncthreads();
    const float m0 = fl[qg * 64 + l31],       m1 = fl[qg * 64 + 32 + l31];
    const float l0 = fl[128 + qg * 64 + l31], l1 = fl[128 + qg * 64 + 32 + l31];
    const float ms = fmaxf(m0, m1);
    const float c0 = __expf((m0 - ms) * scale);
    const float c1 = __expf((m1 - ms) * scale);
    const float inv = 1.f / (c0 * l0 + c1 * l1);
    const float cs = kg ? c1 : c0;
#pragma unroll
    for (int dt = 0; dt < 4; ++dt)
#pragma unroll
        for (int r = 0; r < 16; ++r) oacc[dt][r] *= cs;

    float* ob = reinterpret_cast<float*>(lds + 1024);   // [qg*64+lane][17] padded
#pragma unroll
    for (int dt = 0; dt < 4; ++dt) {
        __syncthreads();
        if (kg == 1) {
            float* dst = ob + (qg * 64 + lane) * 17;
#pragma unroll
            for (int r = 0; r < 16; ++r) dst[r] = oacc[dt][r];
        }
        __syncthreads();
        if (kg == 0) {
            const float* sp = ob + (qg * 64 + lane) * 17;
            const int s = q0 + qg * 32 + l31;
            bf16* orow = attn_out + ((size_t)(b * SEQ + s)) * HID + hh * HD;
#pragma unroll
            for (int t = 0; t < 4; ++t) {
                const float v0 = (oacc[dt][t*4+0] + sp[t*4+0]) * inv;
                const float v1 = (oacc[dt][t*4+1] + sp[t*4+1]) * inv;
                const float v2 = (oacc[dt][t*4+2] + sp[t*4+2]) * inv;
                const float v3 = (oacc[dt][t*4+3] + sp[t*4+3]) * inv;
                uint2 val;
                val.x = pk2(v0, v1);
                val.y = pk2(v2, v3);
                *reinterpret_cast<uint2*>(orow + dt * 32 + t * 8 + h * 4) = val;
            }
        }
    }
}

// ---------- final projection, 8-wave 128x128 tiles: A via global_load_lds, W via cvt ----------
__global__ __launch_bounds__(512) void gemm_o_mfma(const bf16* __restrict__ A,
                                                   const float* __restrict__ W,
                                                   float* __restrict__ C) {
    __shared__ bf16 Asl[4096];
    __shared__ bf16 Bsl[4096];
    const int tid  = threadIdx.x;
    const int wave = tid >> 6;
    const int lane = tid & 63;
    const int quad = lane >> 4;
    const int l15  = lane & 15;
    const int row0 = blockIdx.y * 128;
    const int col0 = blockIdx.x * 128;

    const int sr = tid >> 2;
    const int sc = (tid & 3) * 8;

    const bf16* ag = A + (size_t)(row0 + sr) * HID + sc;
    bf16* al = &Asl[tid * 8];

    f32x4 acc[8];
#pragma unroll
    for (int j = 0; j < 8; ++j) acc[j] = (f32x4){0.f,0.f,0.f,0.f};

    for (int k0 = 0; k0 < HID; k0 += 32) {
        __syncthreads();
        gld_lds16(ag + k0, al);
        {
            const float4* b0 = reinterpret_cast<const float4*>(W + (size_t)(col0 + sr) * HID + k0 + sc);
            cvt8_store(b0[0], b0[1], &Bsl[tid * 8]);
        }
        __syncthreads();
        frag af, bfr[8];
        af = *reinterpret_cast<const frag*>(&Asl[(((wave*16 + l15)*4) + quad) * 8]);
#pragma unroll
        for (int j = 0; j < 8; ++j)
            bfr[j] = *reinterpret_cast<const frag*>(&Bsl[(((j*16 + l15)*4) + quad) * 8]);
#pragma unroll
        for (int j = 0; j < 8; ++j)
            acc[j] = __builtin_amdgcn_mfma_f32_16x16x32_bf16(af, bfr[j], acc[j], 0, 0, 0);
    }

#pragma unroll
    for (int r = 0; r < 4; ++r) {
        const int row = row0 + wave*16 + quad*4 + r;
        float* crow = C + (size_t)row * HID + col0;
#pragma unroll
        for (int j = 0; j < 8; ++j)
            crow[16*j + l15] = acc[j][r];
    }
}

// ---------- launch ----------
extern "C" void kernel_launch(void* const* d_in, const int* in_sizes, int n_in,
                              void* d_out, int out_size, void* d_ws, size_t ws_size,
                              hipStream_t stream) {
    const float* hs = (const float*)d_in[0];
    const float* Wq = (const float*)d_in[1];
    const float* Wk = (const float*)d_in[2];
    const float* Wv = (const float*)d_in[3];
    const float* Wo = (const float*)d_in[4];

    float* out      = (float*)d_out;
    float* out_attn = out;                         // [B,S,H]    8388608 f32 (33.55 MB)
    float* out_k    = out + 8388608;               // [B,1,S,HD]  524288 f32
    float* out_v    = out + 8388608 + 524288;      // [B,1,S,HD]  524288 f32

    // Scratch in d_out's attn region (all consumed before gemm_o writes it):
    bf16* qbuf = (bf16*)d_out;                             // [0 .. 16777216)      roped q bf16
    bf16* kb   = (bf16*)((char*)d_out + 16777216);         // [.. 17825792)        roped k bf16
    bf16* vt   = (bf16*)((char*)d_out + 17825792);         // [.. 18874368)        v^T bf16
    bf16* wqb  = (bf16*)((char*)d_out + 18874368);         // [.. 27262976)        Wq bf16
    bf16* wkb  = (bf16*)((char*)d_out + 27262976);         // [.. 27787264)        Wk bf16
    bf16* wvb  = (bf16*)((char*)d_out + 27787264);         // [.. 28311552)        Wv bf16
    // ws[0..16.78M): hs_bf during {cvt,gemm_qkv}; attn_out during {attn,gemm_o}
    bf16* hsb      = (bf16*)d_ws;
    bf16* attn_out = (bf16*)d_ws;

    cvt_bf16  <<<dim3(6400),                  dim3(256), 0, stream>>>(hs, Wq, Wk, Wv, hsb, wqb, wkb, wvb);
    gemm_qkv  <<<dim3(18, (BB*SEQ)/128),      dim3(512), 0, stream>>>(hsb, wqb, wkb, wvb,
                                                                      qbuf, out_k, out_v, kb, vt);
    attn_mfma <<<dim3(SEQ/64, NH, BB),        dim3(256), 0, stream>>>(qbuf, kb, vt, attn_out);
    gemm_o_mfma<<<dim3(HID/128, (BB*SEQ)/128), dim3(512), 0, stream>>>(attn_out, Wo, out_attn);
}

// Round 9
// 357.915 us; speedup vs baseline: 1.2123x; 1.0553x over previous
//
#include <hip/hip_runtime.h>
#include <hip/hip_bf16.h>

typedef __hip_bfloat16 bf16;

#define NH   16
#define HD   128
#define SEQ  2048
#define BB   2
#define HID  2048

// ln(10000)/64
#define ROPE_C 0.14391156856f

using frag   = __attribute__((ext_vector_type(8))) short;   // 8 bf16 = 4 VGPRs
using f32x4  = __attribute__((ext_vector_type(4))) float;
using f32x16 = __attribute__((ext_vector_type(16))) float;

// ---------- helpers ----------

// pack 8 fp32 -> 8 bf16 (one 16B LDS write)
__device__ __forceinline__ void cvt8_store(const float4 f0, const float4 f1, bf16* dst) {
    union { frag v; bf16 h[8]; } p;
    p.h[0] = __float2bfloat16(f0.x); p.h[1] = __float2bfloat16(f0.y);
    p.h[2] = __float2bfloat16(f0.z); p.h[3] = __float2bfloat16(f0.w);
    p.h[4] = __float2bfloat16(f1.x); p.h[5] = __float2bfloat16(f1.y);
    p.h[6] = __float2bfloat16(f1.z); p.h[7] = __float2bfloat16(f1.w);
    *reinterpret_cast<frag*>(dst) = p.v;
}

// pack 2 fp32 -> 1 dword of 2 bf16
__device__ __forceinline__ unsigned pk2(float a, float b) {
    union { bf16 h[2]; unsigned u; } p;
    p.h[0] = __float2bfloat16(a);
    p.h[1] = __float2bfloat16(b);
    return p.u;
}

// async global->LDS, 16B per lane (dest = wave-uniform base + lane*16)
__device__ __forceinline__ void gld_lds16(const bf16* g, bf16* l) {
    __builtin_amdgcn_global_load_lds(
        (const __attribute__((address_space(1))) void*)g,
        (__attribute__((address_space(3))) void*)l, 16, 0, 0);
}

// ---------- prepass: fp32 -> bf16 for hs, Wq, Wk, Wv ----------
__global__ __launch_bounds__(256) void cvt_bf16(const float* __restrict__ hs,
                                                const float* __restrict__ Wq,
                                                const float* __restrict__ Wk,
                                                const float* __restrict__ Wv,
                                                bf16* __restrict__ hsb,
                                                bf16* __restrict__ wqb,
                                                bf16* __restrict__ wkb,
                                                bf16* __restrict__ wvb) {
    const int blk = blockIdx.x;
    const float* src;
    bf16* dst;
    if (blk < 4096)      { src = hs + (size_t)blk * 2048;          dst = hsb + (size_t)blk * 2048; }
    else if (blk < 6144) { src = Wq + (size_t)(blk - 4096) * 2048; dst = wqb + (size_t)(blk - 4096) * 2048; }
    else if (blk < 6272) { src = Wk + (size_t)(blk - 6144) * 2048; dst = wkb + (size_t)(blk - 6144) * 2048; }
    else                 { src = Wv + (size_t)(blk - 6272) * 2048; dst = wvb + (size_t)(blk - 6272) * 2048; }
    const int t = threadIdx.x * 8;
    const float4 f0 = *reinterpret_cast<const float4*>(src + t);
    const float4 f1 = *reinterpret_cast<const float4*>(src + t + 4);
    cvt8_store(f0, f1, dst + t);
}

// ---------- fused Q/K/V projection: 4-wave 128x128 tiles, 64x64 per wave ----------
// Round-9: wave grid 2x2, acc[4][4] -> 8 ds_read_b128 : 16 MFMA per k-step
// (was 9:8 -> LDS-pipe-bound 3.7x). Staging pure global_load_lds (2 rounds/op).
// B staged with column permutation sigma(r) = (r>>6)*32 + ((r>>5)&1)*64 + (r&31)
// so each wave's 64 cols are RoPE pairs (d, d+64): x1=acc[i][j], x2=acc[i][j+2].
// sigma(r+64) = sigma(r)+32 -> round-1 staging is a constant row offset.
__global__ __launch_bounds__(256, 4) void gemm_qkv(const bf16* __restrict__ A,
                                                   const bf16* __restrict__ Wqb,
                                                   const bf16* __restrict__ Wkb,
                                                   const bf16* __restrict__ Wvb,
                                                   bf16* __restrict__ qout,
                                                   float* __restrict__ Ck,
                                                   float* __restrict__ Cv,
                                                   bf16* __restrict__ kb,
                                                   bf16* __restrict__ vt) {
    __shared__ bf16 Asl[4096];   // 128 rows x 32 k, chunk n at byte n*16
    __shared__ bf16 Bsl[4096];
    const int tid  = threadIdx.x;
    const int wave = tid >> 6;
    const int lane = tid & 63;
    const int quad = lane >> 4;
    const int l15  = lane & 15;
    const int wr   = wave >> 1;       // 0..1 row-group
    const int wc   = wave & 1;        // 0..1 col-group
    const int row0 = blockIdx.y * 128;
    const int bx   = blockIdx.x;
    const bool isq  = bx < 16;
    const bool is_v = (bx == 17);
    const bf16* W   = isq ? Wqb : (is_v ? Wvb : Wkb);
    const int col0  = isq ? bx * 128 : 0;

    const int sr = tid >> 2;          // 0..63
    const int sc = (tid & 3) * 8;     // 0,8,16,24
    const int sg = ((sr >> 5) & 1) * 64 + (sr & 31);   // sigma(sr), sr<64

    const bf16* ag = A + (size_t)(row0 + sr) * HID + sc;
    const bf16* bg = W + (size_t)(col0 + sg) * HID + sc;
    bf16* al = &Asl[tid * 8];
    bf16* bl = &Bsl[tid * 8];

    f32x4 acc[4][4];
#pragma unroll
    for (int i = 0; i < 4; ++i)
#pragma unroll
        for (int j = 0; j < 4; ++j) acc[i][j] = (f32x4){0.f,0.f,0.f,0.f};

    for (int k0 = 0; k0 < HID; k0 += 32) {
        __syncthreads();
        gld_lds16(ag + k0, al);                              // rows sr
        gld_lds16(ag + (size_t)64 * HID + k0, al + 2048);    // rows sr+64
        gld_lds16(bg + k0, bl);                              // cols sigma(sr)
        gld_lds16(bg + (size_t)32 * HID + k0, bl + 2048);    // sigma(sr+64)=sigma+32
        __syncthreads();
        frag af[4], bfr[4];
#pragma unroll
        for (int i = 0; i < 4; ++i)
            af[i] = *reinterpret_cast<const frag*>(&Asl[(((wr*64 + i*16 + l15)*4) + quad) * 8]);
#pragma unroll
        for (int j = 0; j < 4; ++j)
            bfr[j] = *reinterpret_cast<const frag*>(&Bsl[(((wc*64 + j*16 + l15)*4) + quad) * 8]);
#pragma unroll
        for (int i = 0; i < 4; ++i)
#pragma unroll
            for (int j = 0; j < 4; ++j)
                acc[i][j] = __builtin_amdgcn_mfma_f32_16x16x32_bf16(af[i], bfr[j], acc[i][j], 0, 0, 0);
    }

    // wave covers cols {wc*32 + [0,32)} and {+64} (sigma pairing)
    if (isq) {
#pragma unroll
        for (int i = 0; i < 4; ++i)
#pragma unroll
            for (int r = 0; r < 4; ++r) {
                const int row = row0 + wr*64 + i*16 + quad*4 + r;
                const int s = row & (SEQ - 1);
                bf16* crow = qout + (size_t)row * HID + col0;
#pragma unroll
                for (int j = 0; j < 2; ++j) {
                    const int d = wc*32 + 16*j + l15;
                    const float invf = expf(-(float)d * ROPE_C);
                    float sn, cs;
                    sincosf((float)s * invf, &sn, &cs);
                    const float x1 = acc[i][j][r], x2 = acc[i][j+2][r];
                    crow[d]      = __float2bfloat16(x1*cs - x2*sn);
                    crow[d + 64] = __float2bfloat16(x2*cs + x1*sn);
                }
            }
    } else if (is_v) {
#pragma unroll
        for (int i = 0; i < 4; ++i)
#pragma unroll
            for (int r = 0; r < 4; ++r) {
                const int row = row0 + wr*64 + i*16 + quad*4 + r;   // b*SEQ + s
                const int s = row & (SEQ - 1);
                const int b = row >> 11;
                float* crow = Cv + (size_t)row * HD;
#pragma unroll
                for (int j = 0; j < 4; ++j) {
                    const int d = (j >> 1)*64 + wc*32 + (j & 1)*16 + l15;
                    const float val = acc[i][j][r];
                    crow[d] = val;
                    vt[((size_t)b * HD + d) * SEQ + s] = __float2bfloat16(val);
                }
            }
    } else {
#pragma unroll
        for (int i = 0; i < 4; ++i)
#pragma unroll
            for (int r = 0; r < 4; ++r) {
                const int row = row0 + wr*64 + i*16 + quad*4 + r;
                const int s = row & (SEQ - 1);
                float* crow = Ck + (size_t)row * HD;
#pragma unroll
                for (int j = 0; j < 2; ++j) {
                    const int d = wc*32 + 16*j + l15;
                    const float invf = expf(-(float)d * ROPE_C);
                    float sn, cs;
                    sincosf((float)s * invf, &sn, &cs);
                    const float y1 = acc[i][j][r]*cs - acc[i][j+2][r]*sn;
                    const float y2 = acc[i][j+2][r]*cs + acc[i][j][r]*sn;
                    crow[d]      = y1;
                    crow[d + 64] = y2;
                    kb[(size_t)row * HD + d]      = __float2bfloat16(y1);
                    kb[(size_t)row * HD + d + 64] = __float2bfloat16(y2);
                }
            }
    }
}

// ---------- flash MFMA attention, 32x32x16, 4-wave key-split blocks (unchanged, passing) ----------
__global__ __launch_bounds__(256) void attn_mfma(const bf16* __restrict__ qbuf,
                                                 const bf16* __restrict__ kb,
                                                 const bf16* __restrict__ vt,
                                                 bf16* __restrict__ attn_out) {
    __shared__ char lds[32768];

    const int tid  = threadIdx.x;
    const int wave = tid >> 6;
    const int lane = tid & 63;
    const int l31  = lane & 31;
    const int h    = lane >> 5;
    const int qg   = wave & 1;
    const int kg   = wave >> 1;
    const int q0   = blockIdx.x * 64;
    const int hh   = blockIdx.y;      // head
    const int b    = blockIdx.z;

    const bf16* kbb = kb + (size_t)b * SEQ * HD;
    const bf16* vtb = vt + (size_t)b * HD * SEQ;

    // Q B-frags: qfr[c] = Q[qrow = q0+qg*32+l31][dims c*16 + h*8 .. +7]
    frag qfr[8];
    {
        const bf16* qrow = qbuf + ((size_t)(b * SEQ + q0 + qg * 32 + l31)) * HID + hh * HD;
#pragma unroll
        for (int c = 0; c < 8; ++c)
            qfr[c] = *reinterpret_cast<const frag*>(qrow + c * 16 + h * 8);
    }

    // staging: 128 threads (sl) per kg_s half
    const int sl   = tid & 127;
    const int kg_s = tid >> 7;

    // K: 4 x 16B chunks, global-contiguous n = sl + i*128 (global elem = 8n)
    //    n -> key=n>>4, d=(n>>1)&7, hs=n&1 ; LDS L = d*64 + key*2 + hs
    int klof[4];
#pragma unroll
    for (int i = 0; i < 4; ++i) {
        const int n   = sl + i * 128;
        const int key = n >> 4, d = (n >> 1) & 7, hs = n & 1;
        const int L   = d * 64 + key * 2 + hs;
        klof[i] = (kg_s * 8192 + L * 16) ^ (((((key >> 2) ^ d) & 7)) << 4);
    }
    // V: 8 x 8B granules g = sl + i*128: dim=g>>3, ks=(g>>2)&1, m=(g>>1)&1, hs=g&1
    int vlof[8], vgof[8];
#pragma unroll
    for (int i = 0; i < 8; ++i) {
        const int g   = sl + i * 128;
        const int dim = g >> 3, ks = (g >> 2) & 1, m = (g >> 1) & 1, hs = g & 1;
        const int dt  = dim >> 5;
        const int C   = (dt * 2 + ks) * 64 + (dim & 31) * 2 + hs;
        const int B   = 16384 + kg_s * 8192 + C * 16 + m * 8;
        const int xv  = (((dim & 31) >> 2) ^ (dt * 2 + ks)) & 7;
        vlof[i] = B ^ (xv << 4);
        vgof[i] = dim * SEQ + kg_s * 32 + (g & 7) * 4;
    }

    // frag-read base: within-chunk byte (l31*2+h)*16, swizzled (>>7 term);
    // per-chunk (>>10) term applied as compile-time (cb<<4) XOR at use site.
    const int rpos = (l31 * 2 + h) * 16;
    const int rsw  = rpos ^ ((((rpos >> 7) & 7)) << 4);

    f32x16 oacc[4];
#pragma unroll
    for (int dt = 0; dt < 4; ++dt)
#pragma unroll
        for (int r = 0; r < 16; ++r) oacc[dt][r] = 0.f;
    float mrow = -1e30f;
    float lrow = 0.f;
    const float scale = 0.088388347648318433f;   // 1/sqrt(128)

    for (int it = 0; it < SEQ / 64; ++it) {
        __syncthreads();
        {
            const bf16* kp = kbb + (size_t)it * 64 * HD + kg_s * 4096;
            const bf16* vp = vtb + it * 64;
            uint4 krg[4];
            uint2 vrg[8];
#pragma unroll
            for (int i = 0; i < 4; ++i)
                krg[i] = *reinterpret_cast<const uint4*>(kp + (sl + i * 128) * 8);
#pragma unroll
            for (int i = 0; i < 8; ++i)
                vrg[i] = *reinterpret_cast<const uint2*>(vp + vgof[i]);
#pragma unroll
            for (int i = 0; i < 4; ++i)
                *reinterpret_cast<uint4*>(lds + klof[i]) = krg[i];
#pragma unroll
            for (int i = 0; i < 8; ++i)
                *reinterpret_cast<uint2*>(lds + vlof[i]) = vrg[i];
        }
        __syncthreads();

        // S^T (32 keys x 32 qrows): rows = keys (r&3)+8*(r>>2)+4h, col = l31
        f32x16 sacc;
#pragma unroll
        for (int r = 0; r < 16; ++r) sacc[r] = 0.f;
#pragma unroll
        for (int c = 0; c < 8; ++c) {
            const frag kf = *reinterpret_cast<const frag*>(
                lds + kg * 8192 + c * 1024 + (rsw ^ (c << 4)));
            sacc = __builtin_amdgcn_mfma_f32_32x32x16_bf16(kf, qfr[c], sacc, 0, 0, 0);
        }

        // online softmax for qrow = l31 (partner h via xor-32)
        float mx = -1e30f;
#pragma unroll
        for (int r = 0; r < 16; ++r) mx = fmaxf(mx, sacc[r]);
        mx = fmaxf(mx, __shfl_xor(mx, 32));
        const bool skip = (bool)__all(mx - mrow <= 90.0f);   // e^(90*scale) ~ e^8
        const float mn = skip ? mrow : fmaxf(mrow, mx);
        const float al = skip ? 1.f : __expf((mrow - mn) * scale);
        float p[16];
        float ps = 0.f;
#pragma unroll
        for (int r = 0; r < 16; ++r) {
            p[r] = __expf((sacc[r] - mn) * scale);
            ps += p[r];
        }
        ps += __shfl_xor(ps, 32);
        lrow = lrow * al + ps;
        mrow = mn;

        // PV B-frags: pb[ks] elem j = p[8ks+j] (pi-permuted V key order)
        frag pb[2];
#pragma unroll
        for (int ks = 0; ks < 2; ++ks) {
            union { unsigned u[4]; frag f; } pf;
#pragma unroll
            for (int w = 0; w < 4; ++w)
                pf.u[w] = pk2(p[8 * ks + 2 * w], p[8 * ks + 2 * w + 1]);
            pb[ks] = pf.f;
        }

        if (!skip)
#pragma unroll
            for (int dt = 0; dt < 4; ++dt)
#pragma unroll
                for (int r = 0; r < 16; ++r) oacc[dt][r] *= al;

        // O^T += V^T P^T
#pragma unroll
        for (int dt = 0; dt < 4; ++dt)
#pragma unroll
            for (int ks = 0; ks < 2; ++ks) {
                const int cb = dt * 2 + ks;
                const frag vf = *reinterpret_cast<const frag*>(
                    lds + 16384 + kg * 8192 + cb * 1024 + (rsw ^ (cb << 4)));
                oacc[dt] = __builtin_amdgcn_mfma_f32_32x32x16_bf16(vf, pb[ks], oacc[dt], 0, 0, 0);
            }
    }

    // ---- flash-decoding merge across kg pairs ----
    __syncthreads();
    float* fl = reinterpret_cast<float*>(lds);
    if (h == 0) {
        fl[(qg * 2 + kg) * 32 + l31]       = mrow;
        fl[128 + (qg * 2 + kg) * 32 + l31] = lrow;
    }
    __syncthreads();
    const float m0 = fl[qg * 64 + l31],       m1 = fl[qg * 64 + 32 + l31];
    const float l0 = fl[128 + qg * 64 + l31], l1 = fl[128 + qg * 64 + 32 + l31];
    const float ms = fmaxf(m0, m1);
    const float c0 = __expf((m0 - ms) * scale);
    const float c1 = __expf((m1 - ms) * scale);
    const float inv = 1.f / (c0 * l0 + c1 * l1);
    const float cs = kg ? c1 : c0;
#pragma unroll
    for (int dt = 0; dt < 4; ++dt)
#pragma unroll
        for (int r = 0; r < 16; ++r) oacc[dt][r] *= cs;

    float* ob = reinterpret_cast<float*>(lds + 1024);   // [qg*64+lane][17] padded
#pragma unroll
    for (int dt = 0; dt < 4; ++dt) {
        __syncthreads();
        if (kg == 1) {
            float* dst = ob + (qg * 64 + lane) * 17;
#pragma unroll
            for (int r = 0; r < 16; ++r) dst[r] = oacc[dt][r];
        }
        __syncthreads();
        if (kg == 0) {
            const float* sp = ob + (qg * 64 + lane) * 17;
            const int s = q0 + qg * 32 + l31;
            bf16* orow = attn_out + ((size_t)(b * SEQ + s)) * HID + hh * HD;
#pragma unroll
            for (int t = 0; t < 4; ++t) {
                const float v0 = (oacc[dt][t*4+0] + sp[t*4+0]) * inv;
                const float v1 = (oacc[dt][t*4+1] + sp[t*4+1]) * inv;
                const float v2 = (oacc[dt][t*4+2] + sp[t*4+2]) * inv;
                const float v3 = (oacc[dt][t*4+3] + sp[t*4+3]) * inv;
                uint2 val;
                val.x = pk2(v0, v1);
                val.y = pk2(v2, v3);
                *reinterpret_cast<uint2*>(orow + dt * 32 + t * 8 + h * 4) = val;
            }
        }
    }
}

// ---------- final projection: 4-wave 128x128 tiles, 64x64 per wave ----------
// A via global_load_lds (2 rounds); W fp32 via cvt staging (2 chunks/thread).
__global__ __launch_bounds__(256, 4) void gemm_o_mfma(const bf16* __restrict__ A,
                                                      const float* __restrict__ W,
                                                      float* __restrict__ C) {
    __shared__ bf16 Asl[4096];
    __shared__ bf16 Bsl[4096];
    const int tid  = threadIdx.x;
    const int wave = tid >> 6;
    const int lane = tid & 63;
    const int quad = lane >> 4;
    const int l15  = lane & 15;
    const int wr   = wave >> 1;
    const int wc   = wave & 1;
    const int row0 = blockIdx.y * 128;
    const int col0 = blockIdx.x * 128;

    const int sr = tid >> 2;          // 0..63
    const int sc = (tid & 3) * 8;

    const bf16* ag = A + (size_t)(row0 + sr) * HID + sc;
    bf16* al = &Asl[tid * 8];
    const float* wg0 = W + (size_t)(col0 + sr) * HID + sc;
    const float* wg1 = wg0 + (size_t)64 * HID;

    f32x4 acc[4][4];
#pragma unroll
    for (int i = 0; i < 4; ++i)
#pragma unroll
        for (int j = 0; j < 4; ++j) acc[i][j] = (f32x4){0.f,0.f,0.f,0.f};

    for (int k0 = 0; k0 < HID; k0 += 32) {
        __syncthreads();
        gld_lds16(ag + k0, al);
        gld_lds16(ag + (size_t)64 * HID + k0, al + 2048);
        {
            const float4* b0 = reinterpret_cast<const float4*>(wg0 + k0);
            const float4* b1 = reinterpret_cast<const float4*>(wg1 + k0);
            cvt8_store(b0[0], b0[1], &Bsl[tid * 8]);
            cvt8_store(b1[0], b1[1], &Bsl[tid * 8 + 2048]);
        }
        __syncthreads();
        frag af[4], bfr[4];
#pragma unroll
        for (int i = 0; i < 4; ++i)
            af[i] = *reinterpret_cast<const frag*>(&Asl[(((wr*64 + i*16 + l15)*4) + quad) * 8]);
#pragma unroll
        for (int j = 0; j < 4; ++j)
            bfr[j] = *reinterpret_cast<const frag*>(&Bsl[(((wc*64 + j*16 + l15)*4) + quad) * 8]);
#pragma unroll
        for (int i = 0; i < 4; ++i)
#pragma unroll
            for (int j = 0; j < 4; ++j)
                acc[i][j] = __builtin_amdgcn_mfma_f32_16x16x32_bf16(af[i], bfr[j], acc[i][j], 0, 0, 0);
    }

#pragma unroll
    for (int i = 0; i < 4; ++i)
#pragma unroll
        for (int r = 0; r < 4; ++r) {
            const int row = row0 + wr*64 + i*16 + quad*4 + r;
            float* crow = C + (size_t)row * HID + col0 + wc*64;
#pragma unroll
            for (int j = 0; j < 4; ++j)
                crow[16*j + l15] = acc[i][j][r];
        }
}

// ---------- launch ----------
extern "C" void kernel_launch(void* const* d_in, const int* in_sizes, int n_in,
                              void* d_out, int out_size, void* d_ws, size_t ws_size,
                              hipStream_t stream) {
    const float* hs = (const float*)d_in[0];
    const float* Wq = (const float*)d_in[1];
    const float* Wk = (const float*)d_in[2];
    const float* Wv = (const float*)d_in[3];
    const float* Wo = (const float*)d_in[4];

    float* out      = (float*)d_out;
    float* out_attn = out;                         // [B,S,H]    8388608 f32 (33.55 MB)
    float* out_k    = out + 8388608;               // [B,1,S,HD]  524288 f32
    float* out_v    = out + 8388608 + 524288;      // [B,1,S,HD]  524288 f32

    // Scratch in d_out's attn region (all consumed before gemm_o writes it):
    bf16* qbuf = (bf16*)d_out;                             // [0 .. 16777216)      roped q bf16
    bf16* kb   = (bf16*)((char*)d_out + 16777216);         // [.. 17825792)        roped k bf16
    bf16* vt   = (bf16*)((char*)d_out + 17825792);         // [.. 18874368)        v^T bf16
    bf16* wqb  = (bf16*)((char*)d_out + 18874368);         // [.. 27262976)        Wq bf16
    bf16* wkb  = (bf16*)((char*)d_out + 27262976);         // [.. 27787264)        Wk bf16
    bf16* wvb  = (bf16*)((char*)d_out + 27787264);         // [.. 28311552)        Wv bf16
    // ws[0..16.78M): hs_bf during {cvt,gemm_qkv}; attn_out during {attn,gemm_o}
    bf16* hsb      = (bf16*)d_ws;
    bf16* attn_out = (bf16*)d_ws;

    cvt_bf16  <<<dim3(6400),                  dim3(256), 0, stream>>>(hs, Wq, Wk, Wv, hsb, wqb, wkb, wvb);
    gemm_qkv  <<<dim3(18, (BB*SEQ)/128),      dim3(256), 0, stream>>>(hsb, wqb, wkb, wvb,
                                                                      qbuf, out_k, out_v, kb, vt);
    attn_mfma <<<dim3(SEQ/64, NH, BB),        dim3(256), 0, stream>>>(qbuf, kb, vt, attn_out);
    gemm_o_mfma<<<dim3(HID/128, (BB*SEQ)/128), dim3(256), 0, stream>>>(attn_out, Wo, out_attn);
}